// Round 5
// baseline (214.335 us; speedup 1.0000x reference)
//
#include <hip/hip_runtime.h>
#include <hip/hip_bf16.h>

namespace {

constexpr int B = 32, S = 512, E = 512, H = 8, P = 64, FF = 1536;
constexpr int BS = B * S;

typedef short v8s __attribute__((ext_vector_type(8)));
typedef float v4f __attribute__((ext_vector_type(4)));

__device__ __forceinline__ float bf2f(unsigned short u) {
  return __uint_as_float(((unsigned int)u) << 16);
}
__device__ __forceinline__ unsigned short f2bf(float f) {
  __hip_bfloat16 h = __float2bfloat16(f);
  return *reinterpret_cast<unsigned short*>(&h);
}

__device__ __forceinline__ void gl_lds16(const unsigned short* g, unsigned short* l) {
  __builtin_amdgcn_global_load_lds((const __attribute__((address_space(1))) unsigned int*)g,
                                   (__attribute__((address_space(3))) unsigned int*)l, 16, 0, 0);
}

// ---------------- prep: weight transposes (blocks 0..447) + x->bf16/colsum (448..703) ----
__global__ __launch_bounds__(256) void k_prep(const float* __restrict__ w1, const float* __restrict__ w2,
                                              const float* __restrict__ wv, const float* __restrict__ x,
                                              unsigned short* __restrict__ w1t, unsigned short* __restrict__ w2t,
                                              unsigned short* __restrict__ wvt, unsigned short* __restrict__ xb,
                                              float* __restrict__ xsump) {
  __shared__ float tile[64][65];
  int id = blockIdx.x;
  int t = threadIdx.x;
  if (id >= 448) {
    int i = id - 448;
    int b = i >> 3, ch = i & 7;
    int c4 = (t & 127) * 4;
    int rh = t >> 7;
    const float* xp = x + ((size_t)b * S + ch * 64 + rh * 32) * E;
    unsigned short* xbp = xb + ((size_t)b * S + ch * 64 + rh * 32) * E;
    float ax = 0.f, ay = 0.f, az = 0.f, aw = 0.f;
    for (int s = 0; s < 32; ++s) {
      float4 v = *(const float4*)(xp + (size_t)s * E + c4);
      ax += v.x; ay += v.y; az += v.z; aw += v.w;
      ushort4 u;
      u.x = f2bf(v.x); u.y = f2bf(v.y); u.z = f2bf(v.z); u.w = f2bf(v.w);
      *(ushort4*)(xbp + (size_t)s * E + c4) = u;
    }
    float* xs = xsump + ((size_t)b * 16 + ch * 2 + rh) * E + c4;
    xs[0] = ax; xs[1] = ay; xs[2] = az; xs[3] = aw;
    return;
  }
  const float* inp;
  unsigned short* outp;
  int R, C, bx, by;
  size_t zo = 0;
  if (id < 192) {
    inp = w1; outp = w1t; R = 512; C = 1536; bx = id % 24; by = id / 24;
  } else if (id < 384) {
    int i = id - 192;
    inp = w2; outp = w2t; R = 1536; C = 512; bx = i & 7; by = i >> 3;
  } else {
    int i = id - 384;
    inp = wv; outp = wvt; R = 512; C = 64; bx = 0; by = i & 7; zo = (size_t)(i >> 3) * (512 * 64);
  }
  int c0 = bx * 64, r0 = by * 64;
#pragma unroll
  for (int j = 0; j < 4; ++j) {
    int i = t + j * 256;
    int rr = i >> 4, c4 = i & 15;
    float4 v = *(const float4*)(inp + zo + (size_t)(r0 + rr) * C + c0 + c4 * 4);
    tile[rr][c4 * 4 + 0] = v.x;
    tile[rr][c4 * 4 + 1] = v.y;
    tile[rr][c4 * 4 + 2] = v.z;
    tile[rr][c4 * 4 + 3] = v.w;
  }
  __syncthreads();
#pragma unroll
  for (int j = 0; j < 4; ++j) {
    int u = t + j * 256;
    int cr = u >> 4, q = u & 15;
    ushort4 o;
    o.x = f2bf(tile[q * 4 + 0][cr]);
    o.y = f2bf(tile[q * 4 + 1][cr]);
    o.z = f2bf(tile[q * 4 + 2][cr]);
    o.w = f2bf(tile[q * 4 + 3][cr]);
    *(ushort4*)(outp + zo + (size_t)(c0 + cr) * R + r0 + q * 4) = o;
  }
}

// ksum[p]=sum_e xsum[b,e]*wk[h,e,p]; wqk[b,h,e]=0.125*sum_p wq[h,e,p]*ksum[p]; zero sqnorm
__global__ __launch_bounds__(256) void k_wqk(const float* __restrict__ xsump, const float* __restrict__ wq,
                                             const float* __restrict__ wk, float* __restrict__ wqk,
                                             float* __restrict__ sqnorm) {
  int b = blockIdx.x, h = blockIdx.y, t = threadIdx.x;
  if (b == 0 && h == 0 && t < 8) sqnorm[t] = 0.f;
  __shared__ float xsl[E];
  __shared__ float ksp[4][64];
  __shared__ float ks[64];
#pragma unroll
  for (int j = 0; j < 2; ++j) {
    int e = t + j * 256;
    float s = 0.f;
#pragma unroll
    for (int c = 0; c < 16; ++c) s += xsump[((size_t)b * 16 + c) * E + e];
    xsl[e] = s;
  }
  __syncthreads();
  {
    const float* wkh = wk + (size_t)h * E * P;
    int p = t & 63, ec = t >> 6;
    float a = 0.f;
    for (int e = ec * 128; e < ec * 128 + 128; ++e) a += xsl[e] * wkh[e * 64 + p];
    ksp[ec][p] = a;
  }
  __syncthreads();
  if (t < 64) ks[t] = ksp[0][t] + ksp[1][t] + ksp[2][t] + ksp[3][t];
  __syncthreads();
  const float* wqh = wq + (size_t)h * E * P;
#pragma unroll
  for (int j = 0; j < 2; ++j) {
    int e = t + j * 256;
    float a = 0.f;
#pragma unroll 8
    for (int pp = 0; pp < P; ++pp) a += wqh[e * 64 + pp] * ks[pp];
    wqk[((size_t)b * H + h) * E + e] = a * 0.125f;
  }
}

// scores[b,h,s] = xb[b,s,:] . wqk[b,h,:]
__global__ __launch_bounds__(256) void k_scores(const unsigned short* __restrict__ xb,
                                                const float* __restrict__ wqk, float* __restrict__ scores) {
  int b = blockIdx.x, s0 = blockIdx.y * 64, t = threadIdx.x;
  __shared__ float xs[64][68];
  __shared__ float wt[8][68];
  float acc[2] = {0.f, 0.f};
  for (int ec = 0; ec < E; ec += 64) {
    {
      int row = t >> 2, cg = (t & 3) * 16;
      v8s v0 = *(const v8s*)(xb + ((size_t)b * S + s0 + row) * E + ec + cg);
      v8s v1 = *(const v8s*)(xb + ((size_t)b * S + s0 + row) * E + ec + cg + 8);
      float4 f0, f1, f2, f3;
      f0.x = bf2f((unsigned short)v0[0]); f0.y = bf2f((unsigned short)v0[1]);
      f0.z = bf2f((unsigned short)v0[2]); f0.w = bf2f((unsigned short)v0[3]);
      f1.x = bf2f((unsigned short)v0[4]); f1.y = bf2f((unsigned short)v0[5]);
      f1.z = bf2f((unsigned short)v0[6]); f1.w = bf2f((unsigned short)v0[7]);
      f2.x = bf2f((unsigned short)v1[0]); f2.y = bf2f((unsigned short)v1[1]);
      f2.z = bf2f((unsigned short)v1[2]); f2.w = bf2f((unsigned short)v1[3]);
      f3.x = bf2f((unsigned short)v1[4]); f3.y = bf2f((unsigned short)v1[5]);
      f3.z = bf2f((unsigned short)v1[6]); f3.w = bf2f((unsigned short)v1[7]);
      *(float4*)&xs[row][cg] = f0;
      *(float4*)&xs[row][cg + 4] = f1;
      *(float4*)&xs[row][cg + 8] = f2;
      *(float4*)&xs[row][cg + 12] = f3;
    }
    if (t < 128) {
      int hr = t >> 4, c4 = t & 15;
      float4 v = *(const float4*)(wqk + ((size_t)b * H + hr) * E + ec + c4 * 4);
      *(float4*)&wt[hr][c4 * 4] = v;
    }
    __syncthreads();
#pragma unroll
    for (int j = 0; j < 2; ++j) {
      int o = t + j * 256;
      int sl = o >> 3, hh = o & 7;
      float a = 0.f;
#pragma unroll
      for (int c4 = 0; c4 < 16; ++c4) {
        float4 xa = *(const float4*)&xs[sl][c4 * 4];
        float4 wa = *(const float4*)&wt[hh][c4 * 4];
        a += xa.x * wa.x + xa.y * wa.y + xa.z * wa.z + xa.w * wa.w;
      }
      acc[j] += a;
    }
    __syncthreads();
  }
#pragma unroll
  for (int j = 0; j < 2; ++j) {
    int o = t + j * 256;
    int sl = o >> 3, hh = o & 7;
    scores[((size_t)b * H + hh) * S + s0 + sl] = acc[j];
  }
}

__global__ __launch_bounds__(256) void k_softmax(const float* __restrict__ scores, float* __restrict__ attw,
                                                 float* __restrict__ att_out) {
  int bh = blockIdx.x, t = threadIdx.x;
  int b = bh >> 3, h = bh & 7;
  float v0 = scores[(size_t)bh * S + t];
  float v1 = scores[(size_t)bh * S + t + 256];
  float m = fmaxf(v0, v1);
#pragma unroll
  for (int off = 32; off; off >>= 1) m = fmaxf(m, __shfl_xor(m, off));
  __shared__ float rm[4], rs[4];
  if ((t & 63) == 0) rm[t >> 6] = m;
  __syncthreads();
  m = fmaxf(fmaxf(rm[0], rm[1]), fmaxf(rm[2], rm[3]));
  float e0 = __expf(v0 - m), e1 = __expf(v1 - m);
  float sm = e0 + e1;
#pragma unroll
  for (int off = 32; off; off >>= 1) sm += __shfl_xor(sm, off);
  if ((t & 63) == 0) rs[t >> 6] = sm;
  __syncthreads();
  float inv = 1.f / (rs[0] + rs[1] + rs[2] + rs[3]);
  float a0 = e0 * inv, a1 = e1 * inv;
  attw[(size_t)bh * S + t] = a0;
  attw[(size_t)bh * S + t + 256] = a1;
  att_out[((size_t)b * S + t) * H + h] = a0;
  att_out[((size_t)b * S + t + 256) * H + h] = a1;
}

// ---------------- MFMA GEMM core: BK=32, 3-buffer LDS ring, depth-2 prefetch,
// counted vmcnt(4), 1 barrier/K-step, read-identity LDS slots (conflict-free b128).
template <int KD>
__device__ __forceinline__ void gemm_tile_p3(const unsigned short* __restrict__ A,
                                             const unsigned short* __restrict__ Bt,
                                             int lda, int ldb, int m0, int n0,
                                             unsigned short* As, unsigned short* Bs, v4f acc[4][4]) {
  const int t = threadIdx.x;
  const int l = t & 63, w = t >> 6;
  const int wr = w >> 1, wc = w & 1;
  const int srcrow = l & 15, srcg = l >> 4;  // slot = read-identity
  constexpr int NT = KD / 32;
  auto stage = [&](int buf, int tt) {
    int kc = tt * 32;
#pragma unroll
    for (int cc = 0; cc < 2; ++cc) {
      int c = w * 2 + cc;  // chunk of 16 rows (1 KB)
      gl_lds16(A + (size_t)(m0 + c * 16 + srcrow) * lda + kc + srcg * 8, As + buf * 4096 + c * 512);
      gl_lds16(Bt + (size_t)(n0 + c * 16 + srcrow) * ldb + kc + srcg * 8, Bs + buf * 4096 + c * 512);
    }
  };
  stage(0, 0);
  stage(1, 1);
  int sb = 2, rb = 0;
  for (int tt = 0; tt < NT; ++tt) {
    if (tt < NT - 1) {
      asm volatile("s_waitcnt vmcnt(4)" ::: "memory");  // buf tt landed; next-buf loads stay in flight
    } else {
      asm volatile("s_waitcnt vmcnt(0)" ::: "memory");
    }
    __builtin_amdgcn_s_barrier();
    if (tt + 2 < NT) {
      stage(sb, tt + 2);  // depth-2: ~2 K-step phases to land
      sb = (sb == 2) ? 0 : sb + 1;
    }
    const unsigned short* Ab = As + rb * 4096;
    const unsigned short* Bb = Bs + rb * 4096;
    rb = (rb == 2) ? 0 : rb + 1;
    v8s af[4], bfr[4];
#pragma unroll
    for (int i = 0; i < 4; ++i) {
      af[i] = *(const v8s*)(Ab + (wr * 4 + i) * 512 + l * 8);
      bfr[i] = *(const v8s*)(Bb + (wc * 4 + i) * 512 + l * 8);
    }
    __builtin_amdgcn_s_setprio(1);
#pragma unroll
    for (int i = 0; i < 4; ++i)
#pragma unroll
      for (int j = 0; j < 4; ++j)
        acc[i][j] = __builtin_amdgcn_mfma_f32_16x16x32_bf16(af[i], bfr[j], acc[i][j], 0, 0, 0);
    __builtin_amdgcn_s_setprio(0);
  }
}

// V-projection GEMM: vb[(b,s)][h*64+p] = bf16((xb @ wv)*attw); sqnorm[h] += sum o^2
__global__ __launch_bounds__(256) void k_gemm_v(const unsigned short* __restrict__ xb,
                                                const unsigned short* __restrict__ wvt,
                                                const float* __restrict__ attw, unsigned short* __restrict__ vb,
                                                float* __restrict__ sqnorm) {
  __shared__ alignas(16) unsigned short As[12288], Bs[12288];
  int m0 = blockIdx.x * 128, n0 = blockIdx.y * 128;
  v4f acc[4][4] = {};
  gemm_tile_p3<512>(xb, wvt, 512, 512, m0, n0, As, Bs, acc);
  int t = threadIdx.x, l = t & 63, w = t >> 6, wr = w >> 1, wc = w & 1;
  int h = blockIdx.y * 2 + wc;
  float ssq = 0.f;
#pragma unroll
  for (int i = 0; i < 4; ++i) {
#pragma unroll
    for (int q = 0; q < 4; ++q) {
      int row = m0 + wr * 64 + i * 16 + (l >> 4) * 4 + q;
      int b = row >> 9, s = row & 511;
      float aw = attw[(size_t)(b * 8 + h) * 512 + s];
#pragma unroll
      for (int j = 0; j < 4; ++j) {
        int gc = n0 + wc * 64 + j * 16 + (l & 15);
        float o = acc[i][j][q] * aw;
        ssq += o * o;
        vb[(size_t)row * 512 + gc] = f2bf(o);
      }
    }
  }
#pragma unroll
  for (int off = 32; off; off >>= 1) ssq += __shfl_xor(ssq, off);
  if (l == 0) atomicAdd(&sqnorm[h], ssq);
}

// LN0 (wave per row, IN-PLACE over xb): xh := bf16(LN(perm(vb)*hs + xh))
__global__ __launch_bounds__(256) void k_ln0(const unsigned short* __restrict__ vb,
                                             unsigned short* xh,
                                             const float* __restrict__ sqnorm, const float* __restrict__ g,
                                             const float* __restrict__ bb) {
  __shared__ unsigned short perm[4][512];
  int t = threadIdx.x, w = t >> 6, l = t & 63;
  int r = blockIdx.x * 4 + w;
  *(v8s*)&perm[w][l * 8] = *(const v8s*)(vb + (size_t)r * 512 + l * 8);
  __syncthreads();
  v8s xv = *(const v8s*)(xh + (size_t)r * 512 + l * 8);
  float v[8];
#pragma unroll
  for (int j = 0; j < 8; ++j) {
    float hs = rsqrtf(fmaxf(sqnorm[j], 1e-12f));
    v[j] = bf2f(perm[w][j * 64 + l]) * hs + bf2f((unsigned short)xv[j]);
  }
  float sum = 0.f, sq = 0.f;
#pragma unroll
  for (int j = 0; j < 8; ++j) { sum += v[j]; sq += v[j] * v[j]; }
#pragma unroll
  for (int off = 32; off; off >>= 1) {
    sum += __shfl_xor(sum, off);
    sq += __shfl_xor(sq, off);
  }
  float mean = sum * (1.f / E);
  float var = fmaxf(sq * (1.f / E) - mean * mean, 0.f);
  float rstd = rsqrtf(var + 1e-3f);
  float4 g0 = *(const float4*)(g + l * 8), g1 = *(const float4*)(g + l * 8 + 4);
  float4 b0 = *(const float4*)(bb + l * 8), b1 = *(const float4*)(bb + l * 8 + 4);
  float gg[8] = {g0.x, g0.y, g0.z, g0.w, g1.x, g1.y, g1.z, g1.w};
  float bbv[8] = {b0.x, b0.y, b0.z, b0.w, b1.x, b1.y, b1.z, b1.w};
  v8s hv;
#pragma unroll
  for (int j = 0; j < 8; ++j) hv[j] = (short)f2bf((v[j] - mean) * rstd * gg[j] + bbv[j]);
  *(v8s*)(xh + (size_t)r * 512 + l * 8) = hv;
}

// FFN1: p1 = bf16(leaky_relu(hb @ w1 + b1)); rsump[row][by*2+wc] = partial sumsq
__global__ __launch_bounds__(256) void k_ffn1(const unsigned short* __restrict__ hb,
                                              const unsigned short* __restrict__ w1t,
                                              const float* __restrict__ b1, unsigned short* __restrict__ p1,
                                              float* __restrict__ rsump) {
  __shared__ alignas(16) unsigned short As[12288], Bs[12288];
  int m0 = blockIdx.x * 128, n0 = blockIdx.y * 128;
  v4f acc[4][4] = {};
  gemm_tile_p3<512>(hb, w1t, 512, 512, m0, n0, As, Bs, acc);
  int t = threadIdx.x, l = t & 63, w = t >> 6, wr = w >> 1, wc = w & 1;
  int colb = n0 + wc * 64 + (l & 15);
  float bias[4];
#pragma unroll
  for (int j = 0; j < 4; ++j) bias[j] = b1[colb + j * 16];
#pragma unroll
  for (int i = 0; i < 4; ++i) {
#pragma unroll
    for (int q = 0; q < 4; ++q) {
      int row = m0 + wr * 64 + i * 16 + (l >> 4) * 4 + q;
      float ps = 0.f;
#pragma unroll
      for (int j = 0; j < 4; ++j) {
        float v = acc[i][j][q] + bias[j];
        v = v > 0.f ? v : 0.2f * v;
        ps += v * v;
        p1[(size_t)row * FF + colb + j * 16] = f2bf(v);
      }
#pragma unroll
      for (int m = 1; m < 16; m <<= 1) ps += __shfl_xor(ps, m);
      if ((l & 15) == 0) rsump[(size_t)row * 24 + blockIdx.y * 2 + wc] = ps;
    }
  }
}

// FFN2: p2b = bf16((p1 @ w2)*rinv + b2 + hb); rinv computed in-block from rsump
__global__ __launch_bounds__(256) void k_ffn2(const unsigned short* __restrict__ p1,
                                              const unsigned short* __restrict__ w2t,
                                              const float* __restrict__ rsump, const float* __restrict__ b2,
                                              const unsigned short* __restrict__ hb,
                                              unsigned short* __restrict__ p2b) {
  __shared__ alignas(16) unsigned short As[12288], Bs[12288];
  __shared__ float rinv_l[128];
  int m0 = blockIdx.x * 128, n0 = blockIdx.y * 128;
  int t = threadIdx.x;
  if (t < 128) {
    float s = 0.f;
#pragma unroll
    for (int k = 0; k < 24; ++k) s += rsump[(size_t)(m0 + t) * 24 + k];
    rinv_l[t] = rsqrtf(fmaxf(s, 1e-12f));
  }
  v4f acc[4][4] = {};
  gemm_tile_p3<1536>(p1, w2t, 1536, 1536, m0, n0, As, Bs, acc);
  int l = t & 63, w = t >> 6, wr = w >> 1, wc = w & 1;
  int colb = n0 + wc * 64 + (l & 15);
  float bias[4];
#pragma unroll
  for (int j = 0; j < 4; ++j) bias[j] = b2[colb + j * 16];
#pragma unroll
  for (int i = 0; i < 4; ++i) {
#pragma unroll
    for (int q = 0; q < 4; ++q) {
      int row = m0 + wr * 64 + i * 16 + (l >> 4) * 4 + q;
      float rv = rinv_l[row - m0];
#pragma unroll
      for (int j = 0; j < 4; ++j) {
        size_t idx = (size_t)row * 512 + colb + j * 16;
        float o = acc[i][j][q] * rv + bias[j] + bf2f(hb[idx]);
        p2b[idx] = f2bf(o);
      }
    }
  }
}

// LN1 (wave per row): out = LN(p2b)
__global__ __launch_bounds__(256) void k_ln1(const unsigned short* __restrict__ p2b, const float* __restrict__ g,
                                             const float* __restrict__ bb, float* __restrict__ outp) {
  int t = threadIdx.x, w = t >> 6, l = t & 63;
  int r = blockIdx.x * 4 + w;
  v8s pv = *(const v8s*)(p2b + (size_t)r * 512 + l * 8);
  float v[8];
#pragma unroll
  for (int j = 0; j < 8; ++j) v[j] = bf2f((unsigned short)pv[j]);
  float sum = 0.f, sq = 0.f;
#pragma unroll
  for (int j = 0; j < 8; ++j) { sum += v[j]; sq += v[j] * v[j]; }
#pragma unroll
  for (int off = 32; off; off >>= 1) {
    sum += __shfl_xor(sum, off);
    sq += __shfl_xor(sq, off);
  }
  float mean = sum * (1.f / E);
  float var = fmaxf(sq * (1.f / E) - mean * mean, 0.f);
  float rstd = rsqrtf(var + 1e-3f);
  float4 g0 = *(const float4*)(g + l * 8), g1 = *(const float4*)(g + l * 8 + 4);
  float4 b0 = *(const float4*)(bb + l * 8), b1 = *(const float4*)(bb + l * 8 + 4);
  float gg[8] = {g0.x, g0.y, g0.z, g0.w, g1.x, g1.y, g1.z, g1.w};
  float bbv[8] = {b0.x, b0.y, b0.z, b0.w, b1.x, b1.y, b1.z, b1.w};
  float4 o0, o1;
  o0.x = (v[0] - mean) * rstd * gg[0] + bbv[0];
  o0.y = (v[1] - mean) * rstd * gg[1] + bbv[1];
  o0.z = (v[2] - mean) * rstd * gg[2] + bbv[2];
  o0.w = (v[3] - mean) * rstd * gg[3] + bbv[3];
  o1.x = (v[4] - mean) * rstd * gg[4] + bbv[4];
  o1.y = (v[5] - mean) * rstd * gg[5] + bbv[5];
  o1.z = (v[6] - mean) * rstd * gg[6] + bbv[6];
  o1.w = (v[7] - mean) * rstd * gg[7] + bbv[7];
  *(float4*)(outp + (size_t)r * 512 + l * 8) = o0;
  *(float4*)(outp + (size_t)r * 512 + l * 8 + 4) = o1;
}

}  // namespace

extern "C" void kernel_launch(void* const* d_in, const int* in_sizes, int n_in,
                              void* d_out, int out_size, void* d_ws, size_t ws_size,
                              hipStream_t stream) {
  const float* x = (const float*)d_in[0];
  const float* wq = (const float*)d_in[1];
  const float* wk = (const float*)d_in[2];
  const float* wv = (const float*)d_in[3];
  const float* ln0_g = (const float*)d_in[4];
  const float* ln0_b = (const float*)d_in[5];
  const float* w1 = (const float*)d_in[6];
  const float* b1 = (const float*)d_in[7];
  const float* w2 = (const float*)d_in[8];
  const float* b2 = (const float*)d_in[9];
  const float* ln1_g = (const float*)d_in[10];
  const float* ln1_b = (const float*)d_in[11];

  float* att_out = (float*)d_out;                  // [B,S,H]
  float* outp = (float*)d_out + (size_t)B * S * H; // [B,S,E]

  char* ws = (char*)d_ws;
  float* xsump = (float*)(ws + 0);                        // 1 MB  [B][16][E]
  float* wqkb = (float*)(ws + 1048576);                   // 512 KB
  float* scores = (float*)(ws + 1572864);                 // 512 KB
  float* attw = (float*)(ws + 2097152);                   // 512 KB
  float* sqnorm = (float*)(ws + 2621440);                 // 4 KB (pad)
  float* rsump = (float*)(ws + 2625536);                  // 1.5 MB [BS][24]
  unsigned short* w1t = (unsigned short*)(ws + 4263936);  // 1.5 MB [FF][E]
  unsigned short* w2t = (unsigned short*)(ws + 5836800);  // 1.5 MB [E][FF]
  unsigned short* wvt = (unsigned short*)(ws + 7409664);  // 512 KB [H*P][E]
  unsigned short* xb = (unsigned short*)(ws + 7933952);   // 16 MB [BS][E] bf16 (hb aliases after ln0)
  unsigned short* vb = (unsigned short*)(ws + 24711168);  // 16 MB [BS][512] bf16 (p2b aliases)
  unsigned short* p1 = (unsigned short*)(ws + 41488384);  // 48 MB [BS][FF] bf16
  unsigned short* hb = xb;                                // ln0 writes in place
  unsigned short* p2b = vb;                               // vb dead after ln0

  k_prep<<<704, 256, 0, stream>>>(w1, w2, wv, x, w1t, w2t, wvt, xb, xsump);
  k_wqk<<<dim3(B, H), 256, 0, stream>>>(xsump, wq, wk, wqkb, sqnorm);
  k_scores<<<dim3(B, S / 64), 256, 0, stream>>>(xb, wqkb, scores);
  k_softmax<<<B * H, 256, 0, stream>>>(scores, attw, att_out);
  k_gemm_v<<<dim3(BS / 128, 4), 256, 0, stream>>>(xb, wvt, attw, vb, sqnorm);
  k_ln0<<<BS / 4, 256, 0, stream>>>(vb, xb, sqnorm, ln0_g, ln0_b);
  k_ffn1<<<dim3(BS / 128, FF / 128), 256, 0, stream>>>(hb, w1t, b1, p1, rsump);
  k_ffn2<<<dim3(BS / 128, E / 128), 256, 0, stream>>>(p1, w2t, rsump, b2, hb, p2b);
  k_ln1<<<BS / 4, 256, 0, stream>>>(p2b, ln1_g, ln1_b, outp);
}

// Round 6
// 195.889 us; speedup vs baseline: 1.0942x; 1.0942x over previous
//
#include <hip/hip_runtime.h>
#include <hip/hip_bf16.h>

namespace {

constexpr int B = 32, S = 512, E = 512, H = 8, P = 64, FF = 1536;
constexpr int BS = B * S;

typedef short v8s __attribute__((ext_vector_type(8)));
typedef float v4f __attribute__((ext_vector_type(4)));

__device__ __forceinline__ float bf2f(unsigned short u) {
  return __uint_as_float(((unsigned int)u) << 16);
}
__device__ __forceinline__ unsigned short f2bf(float f) {
  __hip_bfloat16 h = __float2bfloat16(f);
  return *reinterpret_cast<unsigned short*>(&h);
}

__device__ __forceinline__ void gl_lds16(const unsigned short* g, unsigned short* l) {
  __builtin_amdgcn_global_load_lds((const __attribute__((address_space(1))) unsigned int*)g,
                                   (__attribute__((address_space(3))) unsigned int*)l, 16, 0, 0);
}

// ---------------- prep: weight transposes (blocks 0..447) + x->bf16/colsum (448..703) ----
__global__ __launch_bounds__(256) void k_prep(const float* __restrict__ w1, const float* __restrict__ w2,
                                              const float* __restrict__ wv, const float* __restrict__ x,
                                              unsigned short* __restrict__ w1t, unsigned short* __restrict__ w2t,
                                              unsigned short* __restrict__ wvt, unsigned short* __restrict__ xb,
                                              float* __restrict__ xsump) {
  __shared__ float tile[64][65];
  int id = blockIdx.x;
  int t = threadIdx.x;
  if (id >= 448) {
    int i = id - 448;
    int b = i >> 3, ch = i & 7;
    int c4 = (t & 127) * 4;
    int rh = t >> 7;
    const float* xp = x + ((size_t)b * S + ch * 64 + rh * 32) * E;
    unsigned short* xbp = xb + ((size_t)b * S + ch * 64 + rh * 32) * E;
    float ax = 0.f, ay = 0.f, az = 0.f, aw = 0.f;
    for (int s = 0; s < 32; ++s) {
      float4 v = *(const float4*)(xp + (size_t)s * E + c4);
      ax += v.x; ay += v.y; az += v.z; aw += v.w;
      ushort4 u;
      u.x = f2bf(v.x); u.y = f2bf(v.y); u.z = f2bf(v.z); u.w = f2bf(v.w);
      *(ushort4*)(xbp + (size_t)s * E + c4) = u;
    }
    float* xs = xsump + ((size_t)b * 16 + ch * 2 + rh) * E + c4;
    xs[0] = ax; xs[1] = ay; xs[2] = az; xs[3] = aw;
    return;
  }
  const float* inp;
  unsigned short* outp;
  int R, C, bx, by;
  size_t zo = 0;
  if (id < 192) {
    inp = w1; outp = w1t; R = 512; C = 1536; bx = id % 24; by = id / 24;
  } else if (id < 384) {
    int i = id - 192;
    inp = w2; outp = w2t; R = 1536; C = 512; bx = i & 7; by = i >> 3;
  } else {
    int i = id - 384;
    inp = wv; outp = wvt; R = 512; C = 64; bx = 0; by = i & 7; zo = (size_t)(i >> 3) * (512 * 64);
  }
  int c0 = bx * 64, r0 = by * 64;
#pragma unroll
  for (int j = 0; j < 4; ++j) {
    int i = t + j * 256;
    int rr = i >> 4, c4 = i & 15;
    float4 v = *(const float4*)(inp + zo + (size_t)(r0 + rr) * C + c0 + c4 * 4);
    tile[rr][c4 * 4 + 0] = v.x;
    tile[rr][c4 * 4 + 1] = v.y;
    tile[rr][c4 * 4 + 2] = v.z;
    tile[rr][c4 * 4 + 3] = v.w;
  }
  __syncthreads();
#pragma unroll
  for (int j = 0; j < 4; ++j) {
    int u = t + j * 256;
    int cr = u >> 4, q = u & 15;
    ushort4 o;
    o.x = f2bf(tile[q * 4 + 0][cr]);
    o.y = f2bf(tile[q * 4 + 1][cr]);
    o.z = f2bf(tile[q * 4 + 2][cr]);
    o.w = f2bf(tile[q * 4 + 3][cr]);
    *(ushort4*)(outp + zo + (size_t)(c0 + cr) * R + r0 + q * 4) = o;
  }
}

// ksum[p]=sum_e xsum[b,e]*wk[h,e,p]; wqk[b,h,e]=0.125*sum_p wq[h,e,p]*ksum[p]; zero sqnorm
__global__ __launch_bounds__(256) void k_wqk(const float* __restrict__ xsump, const float* __restrict__ wq,
                                             const float* __restrict__ wk, float* __restrict__ wqk,
                                             float* __restrict__ sqnorm) {
  int b = blockIdx.x, h = blockIdx.y, t = threadIdx.x;
  if (b == 0 && h == 0 && t < 8) sqnorm[t] = 0.f;
  __shared__ float xsl[E];
  __shared__ float ksp[4][64];
  __shared__ float ks[64];
#pragma unroll
  for (int j = 0; j < 2; ++j) {
    int e = t + j * 256;
    float s = 0.f;
#pragma unroll
    for (int c = 0; c < 16; ++c) s += xsump[((size_t)b * 16 + c) * E + e];
    xsl[e] = s;
  }
  __syncthreads();
  {
    const float* wkh = wk + (size_t)h * E * P;
    int p = t & 63, ec = t >> 6;
    float a = 0.f;
    for (int e = ec * 128; e < ec * 128 + 128; ++e) a += xsl[e] * wkh[e * 64 + p];
    ksp[ec][p] = a;
  }
  __syncthreads();
  if (t < 64) ks[t] = ksp[0][t] + ksp[1][t] + ksp[2][t] + ksp[3][t];
  __syncthreads();
  const float* wqh = wq + (size_t)h * E * P;
#pragma unroll
  for (int j = 0; j < 2; ++j) {
    int e = t + j * 256;
    float a = 0.f;
#pragma unroll 8
    for (int pp = 0; pp < P; ++pp) a += wqh[e * 64 + pp] * ks[pp];
    wqk[((size_t)b * H + h) * E + e] = a * 0.125f;
  }
}

// scores[b,h,s] = xb[b,s,:] . wqk[b,h,:]
__global__ __launch_bounds__(256) void k_scores(const unsigned short* __restrict__ xb,
                                                const float* __restrict__ wqk, float* __restrict__ scores) {
  int b = blockIdx.x, s0 = blockIdx.y * 64, t = threadIdx.x;
  __shared__ float xs[64][68];
  __shared__ float wt[8][68];
  float acc[2] = {0.f, 0.f};
  for (int ec = 0; ec < E; ec += 64) {
    {
      int row = t >> 2, cg = (t & 3) * 16;
      v8s v0 = *(const v8s*)(xb + ((size_t)b * S + s0 + row) * E + ec + cg);
      v8s v1 = *(const v8s*)(xb + ((size_t)b * S + s0 + row) * E + ec + cg + 8);
      float4 f0, f1, f2, f3;
      f0.x = bf2f((unsigned short)v0[0]); f0.y = bf2f((unsigned short)v0[1]);
      f0.z = bf2f((unsigned short)v0[2]); f0.w = bf2f((unsigned short)v0[3]);
      f1.x = bf2f((unsigned short)v0[4]); f1.y = bf2f((unsigned short)v0[5]);
      f1.z = bf2f((unsigned short)v0[6]); f1.w = bf2f((unsigned short)v0[7]);
      f2.x = bf2f((unsigned short)v1[0]); f2.y = bf2f((unsigned short)v1[1]);
      f2.z = bf2f((unsigned short)v1[2]); f2.w = bf2f((unsigned short)v1[3]);
      f3.x = bf2f((unsigned short)v1[4]); f3.y = bf2f((unsigned short)v1[5]);
      f3.z = bf2f((unsigned short)v1[6]); f3.w = bf2f((unsigned short)v1[7]);
      *(float4*)&xs[row][cg] = f0;
      *(float4*)&xs[row][cg + 4] = f1;
      *(float4*)&xs[row][cg + 8] = f2;
      *(float4*)&xs[row][cg + 12] = f3;
    }
    if (t < 128) {
      int hr = t >> 4, c4 = t & 15;
      float4 v = *(const float4*)(wqk + ((size_t)b * H + hr) * E + ec + c4 * 4);
      *(float4*)&wt[hr][c4 * 4] = v;
    }
    __syncthreads();
#pragma unroll
    for (int j = 0; j < 2; ++j) {
      int o = t + j * 256;
      int sl = o >> 3, hh = o & 7;
      float a = 0.f;
#pragma unroll
      for (int c4 = 0; c4 < 16; ++c4) {
        float4 xa = *(const float4*)&xs[sl][c4 * 4];
        float4 wa = *(const float4*)&wt[hh][c4 * 4];
        a += xa.x * wa.x + xa.y * wa.y + xa.z * wa.z + xa.w * wa.w;
      }
      acc[j] += a;
    }
    __syncthreads();
  }
#pragma unroll
  for (int j = 0; j < 2; ++j) {
    int o = t + j * 256;
    int sl = o >> 3, hh = o & 7;
    scores[((size_t)b * H + hh) * S + s0 + sl] = acc[j];
  }
}

__global__ __launch_bounds__(256) void k_softmax(const float* __restrict__ scores, float* __restrict__ attw,
                                                 float* __restrict__ att_out) {
  int bh = blockIdx.x, t = threadIdx.x;
  int b = bh >> 3, h = bh & 7;
  float v0 = scores[(size_t)bh * S + t];
  float v1 = scores[(size_t)bh * S + t + 256];
  float m = fmaxf(v0, v1);
#pragma unroll
  for (int off = 32; off; off >>= 1) m = fmaxf(m, __shfl_xor(m, off));
  __shared__ float rm[4], rs[4];
  if ((t & 63) == 0) rm[t >> 6] = m;
  __syncthreads();
  m = fmaxf(fmaxf(rm[0], rm[1]), fmaxf(rm[2], rm[3]));
  float e0 = __expf(v0 - m), e1 = __expf(v1 - m);
  float sm = e0 + e1;
#pragma unroll
  for (int off = 32; off; off >>= 1) sm += __shfl_xor(sm, off);
  if ((t & 63) == 0) rs[t >> 6] = sm;
  __syncthreads();
  float inv = 1.f / (rs[0] + rs[1] + rs[2] + rs[3]);
  float a0 = e0 * inv, a1 = e1 * inv;
  attw[(size_t)bh * S + t] = a0;
  attw[(size_t)bh * S + t + 256] = a1;
  att_out[((size_t)b * S + t) * H + h] = a0;
  att_out[((size_t)b * S + t + 256) * H + h] = a1;
}

// ---------------- MFMA GEMM core: BM=128, BN=256, BK=64, 8 waves (2Mx4N), 2-buffer LDS,
// counted vmcnt(6) across barriers (T4), setprio around MFMA clusters (T5).
// Chunk = 16 rows x 32 k (1KB). A: 16 chunks, B: 32 chunks per K-tile; 6 gl_lds/thread/K-tile.
// LDS slot l of a chunk holds (row16=l&15, kgranule=l>>4) -> ds_read_b128 is lane-identity
// (fully contiguous 1KB per fragment read, conflict-free).
template <int KD>
__device__ __forceinline__ void gemm_core(const unsigned short* __restrict__ A,
                                          const unsigned short* __restrict__ Bt,
                                          int lda, int ldb, int m0, int n0,
                                          unsigned short* As, unsigned short* Bs, v4f acc[4][4]) {
  const int t = threadIdx.x;
  const int l = t & 63, w = t >> 6;
  const int wm = w >> 2, wn = w & 3;
  const int r15 = l & 15, g4 = l >> 4;
  constexpr int NT = KD / 64;
  auto stage = [&](int buf, int kt) {
#pragma unroll
    for (int cc = 0; cc < 6; ++cc) {
      int c = w * 6 + cc;  // 0..47: A chunks 0..15, B chunks 16..47
      int col = kt * 64 + (c & 1) * 32 + g4 * 8;
      if (c < 16) {
        int row = m0 + (c >> 1) * 16 + r15;
        gl_lds16(A + (size_t)row * lda + col, As + buf * 8192 + c * 512);
      } else {
        int cb = c - 16;
        int row = n0 + (cb >> 1) * 16 + r15;
        gl_lds16(Bt + (size_t)row * ldb + col, Bs + buf * 16384 + cb * 512);
      }
    }
  };
  stage(0, 0);
  for (int tt = 0; tt < NT; ++tt) {
    const int cur = tt & 1;
    if (tt + 1 < NT) {
      stage(cur ^ 1, tt + 1);  // issue next K-tile; stays in flight across the barrier
      asm volatile("s_waitcnt vmcnt(6)" ::: "memory");  // wait current tile only
    } else {
      asm volatile("s_waitcnt vmcnt(0)" ::: "memory");
    }
    __builtin_amdgcn_s_barrier();
    __builtin_amdgcn_sched_barrier(0);
    const unsigned short* Ab = As + cur * 8192;
    const unsigned short* Bb = Bs + cur * 16384;
#pragma unroll
    for (int kk = 0; kk < 2; ++kk) {
      v8s af[4], bf4[4];
#pragma unroll
      for (int i = 0; i < 4; ++i) {
        af[i] = *(const v8s*)(Ab + ((wm * 4 + i) * 2 + kk) * 512 + l * 8);
        bf4[i] = *(const v8s*)(Bb + ((wn * 4 + i) * 2 + kk) * 512 + l * 8);
      }
      __builtin_amdgcn_s_setprio(1);
#pragma unroll
      for (int i = 0; i < 4; ++i)
#pragma unroll
        for (int j = 0; j < 4; ++j)
          acc[i][j] = __builtin_amdgcn_mfma_f32_16x16x32_bf16(af[i], bf4[j], acc[i][j], 0, 0, 0);
      __builtin_amdgcn_s_setprio(0);
    }
    __builtin_amdgcn_s_barrier();  // all reads of buf[cur] done before it is restaged
    __builtin_amdgcn_sched_barrier(0);
  }
}

// V-projection GEMM: vb[(b,s)][h*64+p] = bf16((xb @ wv)*attw); sqnorm[h] += sum o^2
__global__ __launch_bounds__(512, 2) void k_gemm_v(const unsigned short* __restrict__ xb,
                                                   const unsigned short* __restrict__ wvt,
                                                   const float* __restrict__ attw,
                                                   unsigned short* __restrict__ vb,
                                                   float* __restrict__ sqnorm) {
  __shared__ alignas(16) unsigned short As[16384], Bs[32768];
  int m0 = blockIdx.x * 128, n0 = blockIdx.y * 256;
  v4f acc[4][4] = {};
  gemm_core<512>(xb, wvt, 512, 512, m0, n0, As, Bs, acc);
  int t = threadIdx.x, l = t & 63, w = t >> 6, wm = w >> 2, wn = w & 3;
  int h = blockIdx.y * 4 + wn;
  float ssq = 0.f;
#pragma unroll
  for (int i = 0; i < 4; ++i) {
#pragma unroll
    for (int q = 0; q < 4; ++q) {
      int row = m0 + wm * 64 + i * 16 + (l >> 4) * 4 + q;
      int b = row >> 9, s = row & 511;
      float aw = attw[(size_t)(b * 8 + h) * 512 + s];
#pragma unroll
      for (int j = 0; j < 4; ++j) {
        int gc = wn * 64 + j * 16 + (l & 15) + blockIdx.y * 256;
        float o = acc[i][j][q] * aw;
        ssq += o * o;
        vb[(size_t)row * 512 + gc] = f2bf(o);
      }
    }
  }
#pragma unroll
  for (int off = 32; off; off >>= 1) ssq += __shfl_xor(ssq, off);
  if (l == 0) atomicAdd(&sqnorm[h], ssq);
}

// LN0 (wave per row, IN-PLACE over xb): xh := bf16(LN(perm(vb)*hs + xh))
__global__ __launch_bounds__(256) void k_ln0(const unsigned short* __restrict__ vb,
                                             unsigned short* xh,
                                             const float* __restrict__ sqnorm, const float* __restrict__ g,
                                             const float* __restrict__ bb) {
  __shared__ unsigned short perm[4][512];
  int t = threadIdx.x, w = t >> 6, l = t & 63;
  int r = blockIdx.x * 4 + w;
  *(v8s*)&perm[w][l * 8] = *(const v8s*)(vb + (size_t)r * 512 + l * 8);
  __syncthreads();
  v8s xv = *(const v8s*)(xh + (size_t)r * 512 + l * 8);
  float v[8];
#pragma unroll
  for (int j = 0; j < 8; ++j) {
    float hs = rsqrtf(fmaxf(sqnorm[j], 1e-12f));
    v[j] = bf2f(perm[w][j * 64 + l]) * hs + bf2f((unsigned short)xv[j]);
  }
  float sum = 0.f, sq = 0.f;
#pragma unroll
  for (int j = 0; j < 8; ++j) { sum += v[j]; sq += v[j] * v[j]; }
#pragma unroll
  for (int off = 32; off; off >>= 1) {
    sum += __shfl_xor(sum, off);
    sq += __shfl_xor(sq, off);
  }
  float mean = sum * (1.f / E);
  float var = fmaxf(sq * (1.f / E) - mean * mean, 0.f);
  float rstd = rsqrtf(var + 1e-3f);
  float4 g0 = *(const float4*)(g + l * 8), g1 = *(const float4*)(g + l * 8 + 4);
  float4 b0 = *(const float4*)(bb + l * 8), b1 = *(const float4*)(bb + l * 8 + 4);
  float gg[8] = {g0.x, g0.y, g0.z, g0.w, g1.x, g1.y, g1.z, g1.w};
  float bbv[8] = {b0.x, b0.y, b0.z, b0.w, b1.x, b1.y, b1.z, b1.w};
  v8s hv;
#pragma unroll
  for (int j = 0; j < 8; ++j) hv[j] = (short)f2bf((v[j] - mean) * rstd * gg[j] + bbv[j]);
  *(v8s*)(xh + (size_t)r * 512 + l * 8) = hv;
}

// FFN1: p1 = bf16(leaky_relu(hb @ w1 + b1)); rsump[row][by*4+wn] = partial sumsq
__global__ __launch_bounds__(512, 2) void k_ffn1(const unsigned short* __restrict__ hb,
                                                 const unsigned short* __restrict__ w1t,
                                                 const float* __restrict__ b1, unsigned short* __restrict__ p1,
                                                 float* __restrict__ rsump) {
  __shared__ alignas(16) unsigned short As[16384], Bs[32768];
  int m0 = blockIdx.x * 128, n0 = blockIdx.y * 256;
  v4f acc[4][4] = {};
  gemm_core<512>(hb, w1t, 512, 512, m0, n0, As, Bs, acc);
  int t = threadIdx.x, l = t & 63, w = t >> 6, wm = w >> 2, wn = w & 3;
  int colb = n0 + wn * 64 + (l & 15);
  float bias[4];
#pragma unroll
  for (int j = 0; j < 4; ++j) bias[j] = b1[colb + j * 16];
#pragma unroll
  for (int i = 0; i < 4; ++i) {
#pragma unroll
    for (int q = 0; q < 4; ++q) {
      int row = m0 + wm * 64 + i * 16 + (l >> 4) * 4 + q;
      float ps = 0.f;
#pragma unroll
      for (int j = 0; j < 4; ++j) {
        float v = acc[i][j][q] + bias[j];
        v = v > 0.f ? v : 0.2f * v;
        ps += v * v;
        p1[(size_t)row * FF + colb + j * 16] = f2bf(v);
      }
#pragma unroll
      for (int m = 1; m < 16; m <<= 1) ps += __shfl_xor(ps, m);
      if ((l & 15) == 0) rsump[(size_t)row * 24 + blockIdx.y * 4 + wn] = ps;
    }
  }
}

// FFN2: p2b = bf16((p1 @ w2)*rinv + b2 + hb); rinv computed in-block from rsump
__global__ __launch_bounds__(512, 2) void k_ffn2(const unsigned short* __restrict__ p1,
                                                 const unsigned short* __restrict__ w2t,
                                                 const float* __restrict__ rsump, const float* __restrict__ b2,
                                                 const unsigned short* __restrict__ hb,
                                                 unsigned short* __restrict__ p2b) {
  __shared__ alignas(16) unsigned short As[16384], Bs[32768];
  __shared__ float rinv_l[128];
  int m0 = blockIdx.x * 128, n0 = blockIdx.y * 256;
  int t = threadIdx.x;
  if (t < 128) {
    float s = 0.f;
#pragma unroll
    for (int k = 0; k < 24; ++k) s += rsump[(size_t)(m0 + t) * 24 + k];
    rinv_l[t] = rsqrtf(fmaxf(s, 1e-12f));
  }
  v4f acc[4][4] = {};
  gemm_core<1536>(p1, w2t, 1536, 1536, m0, n0, As, Bs, acc);
  int l = t & 63, w = t >> 6, wm = w >> 2, wn = w & 3;
  int colb = n0 + wn * 64 + (l & 15);
  float bias[4];
#pragma unroll
  for (int j = 0; j < 4; ++j) bias[j] = b2[colb + j * 16];
#pragma unroll
  for (int i = 0; i < 4; ++i) {
#pragma unroll
    for (int q = 0; q < 4; ++q) {
      int row = m0 + wm * 64 + i * 16 + (l >> 4) * 4 + q;
      float rv = rinv_l[row - m0];
#pragma unroll
      for (int j = 0; j < 4; ++j) {
        size_t idx = (size_t)row * 512 + colb + j * 16;
        float o = acc[i][j][q] * rv + bias[j] + bf2f(hb[idx]);
        p2b[idx] = f2bf(o);
      }
    }
  }
}

// LN1 (wave per row): out = LN(p2b)
__global__ __launch_bounds__(256) void k_ln1(const unsigned short* __restrict__ p2b, const float* __restrict__ g,
                                             const float* __restrict__ bb, float* __restrict__ outp) {
  int t = threadIdx.x, w = t >> 6, l = t & 63;
  int r = blockIdx.x * 4 + w;
  v8s pv = *(const v8s*)(p2b + (size_t)r * 512 + l * 8);
  float v[8];
#pragma unroll
  for (int j = 0; j < 8; ++j) v[j] = bf2f((unsigned short)pv[j]);
  float sum = 0.f, sq = 0.f;
#pragma unroll
  for (int j = 0; j < 8; ++j) { sum += v[j]; sq += v[j] * v[j]; }
#pragma unroll
  for (int off = 32; off; off >>= 1) {
    sum += __shfl_xor(sum, off);
    sq += __shfl_xor(sq, off);
  }
  float mean = sum * (1.f / E);
  float var = fmaxf(sq * (1.f / E) - mean * mean, 0.f);
  float rstd = rsqrtf(var + 1e-3f);
  float4 g0 = *(const float4*)(g + l * 8), g1 = *(const float4*)(g + l * 8 + 4);
  float4 b0 = *(const float4*)(bb + l * 8), b1 = *(const float4*)(bb + l * 8 + 4);
  float gg[8] = {g0.x, g0.y, g0.z, g0.w, g1.x, g1.y, g1.z, g1.w};
  float bbv[8] = {b0.x, b0.y, b0.z, b0.w, b1.x, b1.y, b1.z, b1.w};
  float4 o0, o1;
  o0.x = (v[0] - mean) * rstd * gg[0] + bbv[0];
  o0.y = (v[1] - mean) * rstd * gg[1] + bbv[1];
  o0.z = (v[2] - mean) * rstd * gg[2] + bbv[2];
  o0.w = (v[3] - mean) * rstd * gg[3] + bbv[3];
  o1.x = (v[4] - mean) * rstd * gg[4] + bbv[4];
  o1.y = (v[5] - mean) * rstd * gg[5] + bbv[5];
  o1.z = (v[6] - mean) * rstd * gg[6] + bbv[6];
  o1.w = (v[7] - mean) * rstd * gg[7] + bbv[7];
  *(float4*)(outp + (size_t)r * 512 + l * 8) = o0;
  *(float4*)(outp + (size_t)r * 512 + l * 8 + 4) = o1;
}

}  // namespace

extern "C" void kernel_launch(void* const* d_in, const int* in_sizes, int n_in,
                              void* d_out, int out_size, void* d_ws, size_t ws_size,
                              hipStream_t stream) {
  const float* x = (const float*)d_in[0];
  const float* wq = (const float*)d_in[1];
  const float* wk = (const float*)d_in[2];
  const float* wv = (const float*)d_in[3];
  const float* ln0_g = (const float*)d_in[4];
  const float* ln0_b = (const float*)d_in[5];
  const float* w1 = (const float*)d_in[6];
  const float* b1 = (const float*)d_in[7];
  const float* w2 = (const float*)d_in[8];
  const float* b2 = (const float*)d_in[9];
  const float* ln1_g = (const float*)d_in[10];
  const float* ln1_b = (const float*)d_in[11];

  float* att_out = (float*)d_out;                  // [B,S,H]
  float* outp = (float*)d_out + (size_t)B * S * H; // [B,S,E]

  char* ws = (char*)d_ws;
  float* xsump = (float*)(ws + 0);                        // 1 MB  [B][16][E]
  float* wqkb = (float*)(ws + 1048576);                   // 512 KB
  float* scores = (float*)(ws + 1572864);                 // 512 KB
  float* attw = (float*)(ws + 2097152);                   // 512 KB
  float* sqnorm = (float*)(ws + 2621440);                 // 4 KB (pad)
  float* rsump = (float*)(ws + 2625536);                  // 1.5 MB [BS][24]
  unsigned short* w1t = (unsigned short*)(ws + 4263936);  // 1.5 MB [FF][E]
  unsigned short* w2t = (unsigned short*)(ws + 5836800);  // 1.5 MB [E][FF]
  unsigned short* wvt = (unsigned short*)(ws + 7409664);  // 512 KB [H*P][E]
  unsigned short* xb = (unsigned short*)(ws + 7933952);   // 16 MB [BS][E] bf16 (hb aliases after ln0)
  unsigned short* vb = (unsigned short*)(ws + 24711168);  // 16 MB [BS][512] bf16 (p2b aliases)
  unsigned short* p1 = (unsigned short*)(ws + 41488384);  // 48 MB [BS][FF] bf16
  unsigned short* hb = xb;                                // ln0 writes in place
  unsigned short* p2b = vb;                               // vb dead after ln0

  k_prep<<<704, 256, 0, stream>>>(w1, w2, wv, x, w1t, w2t, wvt, xb, xsump);
  k_wqk<<<dim3(B, H), 256, 0, stream>>>(xsump, wq, wk, wqkb, sqnorm);
  k_scores<<<dim3(B, S / 64), 256, 0, stream>>>(xb, wqkb, scores);
  k_softmax<<<B * H, 256, 0, stream>>>(scores, attw, att_out);
  k_gemm_v<<<dim3(BS / 128, 2), 512, 0, stream>>>(xb, wvt, attw, vb, sqnorm);
  k_ln0<<<BS / 4, 256, 0, stream>>>(vb, xb, sqnorm, ln0_g, ln0_b);
  k_ffn1<<<dim3(BS / 128, 6), 512, 0, stream>>>(hb, w1t, b1, p1, rsump);
  k_ffn2<<<dim3(BS / 128, 2), 512, 0, stream>>>(p1, w2t, rsump, b2, hb, p2b);
  k_ln1<<<BS / 4, 256, 0, stream>>>(p2b, ln1_g, ln1_b, outp);
}